// Round 6
// baseline (2002.009 us; speedup 1.0000x reference)
//
#include <hip/hip_runtime.h>
#include <math.h>

#define NH 16
#define HD 128
#define CH1 2048
#define CH3 6144
#define CK 64
#define NC 128
#define PCH 132   // LDS pitch for 64x128 tensors (16B-aligned rows)
#define MP 68     // LDS pitch for 64x64 M / N^T

// workspace layout (float offsets)
#define QT_OFF  0u            // tiled q~   [2048 ch][8g][64t][16d]
#define KBT_OFF 16777216u     // kbar^T     [2048 ch][128k][64t]
#define U0_OFF  33554432u     // U0 natural [8192 t][16 h][128 d]
#define Z_OFF   50331648u     // tiled Z    [2048 ch][8g][64t][16d]
#define W_OFF   67108864u     // tiled W    [2048 ch][8g][64t][8s]
#define ECG_OFF 75497472u     // e^{cg63}   [2048 ch][128 k]
#define SLAB_OFF 75759616u    // (unused by scan3; kept for layout stability)

// ---------------------------------------------------------------------------
// Kernel A v2 (unchanged from R5 -- verified): 1024 threads, 4-way d-split
// pair-work with quad shfl reduce, rotated d-columns.
// ---------------------------------------------------------------------------
__global__ __launch_bounds__(1024, 4)
void kda_chunk(const float* __restrict__ mixed, const float* __restrict__ fg,
               const float* __restrict__ beta, const float* __restrict__ cw,
               const float* __restrict__ dtb, const float* __restrict__ alog,
               float* __restrict__ qt_g, float* __restrict__ kbt_g,
               float* __restrict__ u0_g, float* __restrict__ z_g,
               float* __restrict__ w_g, float* __restrict__ ecg_g) {
  __shared__ float lds[36032];
  float* kL  = lds;            // [64][132]
  float* qL  = lds + 8448;     // [64][132], later RHS
  float* cgL = lds + 16896;    // [64][132]
  float* ML  = lds + 25344;    // [64][68]
  float* NT  = lds + 29696;    // [64][68]  (N transposed)
  float* GB  = lds + 34048;    // [768]
  float* bL  = lds + 34816;    // [64]
  float* nrm = lds + 34880;    // [1152]

  const int tid = threadIdx.x;
  const int bid = blockIdx.x;
  const int c = bid >> 4, h = bid & 15;
  const int t0 = c * CK;
  const float ea = __expf(alog[h]);

  // W zero-fill (4096 floats)
  {
    size_t wb = (size_t)bid * 4096;
#pragma unroll
    for (int i = 0; i < 4; ++i) w_g[wb + tid + 1024 * i] = 0.f;
  }

  // (a) g = -exp(alog)*softplus(fg+dtb) -> cgL  (8192 cells)
  for (int it = 0; it < 8; ++it) {
    int cell = tid + (it << 10);
    int d = cell & 127, t = cell >> 7;
    float x = fg[(size_t)(t0 + t) * CH1 + h * HD + d] + dtb[h * HD + d];
    float sp = (x > 20.f) ? x : log1pf(__expf(x));
    cgL[t * PCH + d] = -ea * sp;
  }
  if (tid < 64) bL[tid] = 1.f / (1.f + __expf(-beta[(size_t)(t0 + tid) * NH + h]));
  __syncthreads();

  // inclusive prefix over t (per dim) + ecg writeout (concurrent with (b))
  if (tid < 128) {
    float a = 0.f;
    for (int t = 0; t < 64; ++t) { a += cgL[t * PCH + tid]; cgL[t * PCH + tid] = a; }
    ecg_g[(size_t)bid * 128 + tid] = __expf(a);
  }

  // (b) conv+silu for q (sec0) and k (sec1)  (16384 cells)
  for (int it = 0; it < 16; ++it) {
    int cell = tid + (it << 10);
    int d = cell & 127, sec = (cell >> 7) & 1, t = cell >> 8;
    int ch = sec * CH1 + h * HD + d;
    float4 w4 = ((const float4*)cw)[ch];
    int rbase = t0 + t - 3;
    float acc;
    if (rbase >= 0) {
      const float* mp = mixed + (size_t)rbase * CH3 + ch;
      acc = mp[0] * w4.x + mp[CH3] * w4.y + mp[2 * CH3] * w4.z + mp[3 * CH3] * w4.w;
    } else {
      acc = 0.f;
      if (rbase + 0 >= 0) acc += mixed[(size_t)(rbase + 0) * CH3 + ch] * w4.x;
      if (rbase + 1 >= 0) acc += mixed[(size_t)(rbase + 1) * CH3 + ch] * w4.y;
      if (rbase + 2 >= 0) acc += mixed[(size_t)(rbase + 2) * CH3 + ch] * w4.z;
      acc += mixed[(size_t)(rbase + 3) * CH3 + ch] * w4.w;
    }
    acc = acc / (1.f + __expf(-acc));
    float* dst = (sec == 0) ? qL : kL;
    dst[t * PCH + d] = acc;
  }
  __syncthreads();

  // l2norm partials: 8 threads per (sec,t) row
  {
    int sec = tid >> 9, t = (tid >> 3) & 63, r = tid & 7;
    const float* src = (sec == 0) ? qL : kL;
    float s = 0.f;
#pragma unroll
    for (int i = 0; i < 4; ++i) {
      float4 v = *(const float4*)(src + t * PCH + r * 16 + i * 4);
      s += v.x * v.x + v.y * v.y + v.z * v.z + v.w * v.w;
    }
    nrm[tid] = s;
  }
  __syncthreads();
  if (tid < 128) {
    int sec = tid >> 6, t = tid & 63;
    float s = 0.f;
#pragma unroll
    for (int r = 0; r < 8; ++r) s += nrm[sec * 512 + t * 8 + r];
    float inv = rsqrtf(s + 1e-6f);
    if (sec == 0) inv *= 0.08838834764831845f;  // q scale D^-0.5
    nrm[1024 + tid] = inv;
  }
  __syncthreads();
  for (int it = 0; it < 4; ++it) {
    int f4 = tid + (it << 10);
    int sec = f4 >> 11, t = (f4 >> 5) & 63, d4 = f4 & 31;
    float* dst = (sec == 0) ? qL : kL;
    float inv = nrm[1024 + sec * 64 + t];
    float4 v = *(float4*)(dst + t * PCH + d4 * 4);
    v.x *= inv; v.y *= inv; v.z *= inv; v.w *= inv;
    *(float4*)(dst + t * PCH + d4 * 4) = v;
  }
  __syncthreads();

  // (c) writeouts: q~ (tiled), kbar^T.  64 t x 16 d-groups of 8.
  {
    int tW = tid >> 4, g = tid & 15;
    size_t qb = (size_t)bid * 8192 + (size_t)(g >> 1) * 1024 + tW * 16 + (g & 1) * 8;
    size_t kb = (size_t)bid * 8192;
#pragma unroll
    for (int i = 0; i < 2; ++i) {
      int d = g * 8 + 4 * i;
      float4 qv = *(const float4*)(qL + tW * PCH + d);
      float4 cg4 = *(const float4*)(cgL + tW * PCH + d);
      float4 o;
      o.x = qv.x * __expf(cg4.x); o.y = qv.y * __expf(cg4.y);
      o.z = qv.z * __expf(cg4.z); o.w = qv.w * __expf(cg4.w);
      *(float4*)(qt_g + qb + 4 * i) = o;
      float4 kv = *(const float4*)(kL + tW * PCH + d);
      float4 c63 = *(const float4*)(cgL + 63 * PCH + d);
      kbt_g[kb + (size_t)(d + 0) * 64 + tW] = kv.x * __expf(c63.x - cg4.x);
      kbt_g[kb + (size_t)(d + 1) * 64 + tW] = kv.y * __expf(c63.y - cg4.y);
      kbt_g[kb + (size_t)(d + 2) * 64 + tW] = kv.z * __expf(c63.z - cg4.z);
      kbt_g[kb + (size_t)(d + 3) * 64 + tW] = kv.w * __expf(c63.w - cg4.w);
    }
  }

  // (d) pair-work: A (strict lower, scaled by b -> M) and W (incl lower).
  // 136 lower-tri 4x4 (t,s) tiles x 4-way d-split = 544 lanes; quad shfl reduce.
  if (tid < 544) {
    int L = tid >> 2, dh = tid & 3;
    int tt = (int)((sqrtf(8.f * L + 1.f) - 1.f) * 0.5f);
    while ((tt + 1) * (tt + 2) / 2 <= L) ++tt;
    while (tt * (tt + 1) / 2 > L) --tt;
    int ss = L - tt * (tt + 1) / 2;
    int taD = tt * 4, saD = ss * 4;
    float accA[16], accW[16];
#pragma unroll
    for (int i = 0; i < 16; ++i) { accA[i] = 0.f; accW[i] = 0.f; }
    for (int s4 = 0; s4 < 8; ++s4) {
      // rotated d-column: quad lanes 8 words apart, consecutive tiles offset
      int d = (dh << 5) + (((s4 + L + (dh << 1)) & 7) << 2);
      float ks4v[4][4], cs4v[4][4];
#pragma unroll
      for (int j = 0; j < 4; ++j) {
        *(float4*)ks4v[j] = *(const float4*)(kL + (saD + j) * PCH + d);
        *(float4*)cs4v[j] = *(const float4*)(cgL + (saD + j) * PCH + d);
      }
#pragma unroll
      for (int i = 0; i < 4; ++i) {
        float kt4[4], qt4[4], ct4[4];
        *(float4*)kt4 = *(const float4*)(kL + (taD + i) * PCH + d);
        *(float4*)qt4 = *(const float4*)(qL + (taD + i) * PCH + d);
        *(float4*)ct4 = *(const float4*)(cgL + (taD + i) * PCH + d);
#pragma unroll
        for (int j = 0; j < 4; ++j)
#pragma unroll
          for (int dd = 0; dd < 4; ++dd) {
            float diff = ct4[dd] - cs4v[j][dd];
            float e = __expf(fminf(diff, 0.f));
            float m = e * ks4v[j][dd];
            accA[i * 4 + j] += kt4[dd] * m;
            accW[i * 4 + j] += qt4[dd] * m;
          }
      }
    }
    // quad-local reduction over the 4 d-splits (lanes 4L+dh, same wave)
#pragma unroll
    for (int i = 0; i < 16; ++i) {
      accA[i] += __shfl_xor(accA[i], 1);
      accA[i] += __shfl_xor(accA[i], 2);
      accW[i] += __shfl_xor(accW[i], 1);
      accW[i] += __shfl_xor(accW[i], 2);
    }
    if (dh == 0) {
      size_t wb = (size_t)bid * 4096;
#pragma unroll
      for (int i = 0; i < 4; ++i)
#pragma unroll
        for (int j = 0; j < 4; ++j) {
          int t = taD + i, s = saD + j;
          if (s < t) ML[t * MP + s] = bL[t] * accA[i * 4 + j];
          float wv = (s <= t) ? accW[i * 4 + j] : 0.f;
          w_g[wb + (size_t)(s >> 3) * 512 + t * 8 + (s & 7)] = wv;
        }
    }
  }
  __syncthreads();

  // (e) N = (I + B A)^-1, stored transposed in NT
  for (int i = tid; i < 4352; i += 1024) NT[i] = 0.f;
  __syncthreads();
  if (tid < 64) {
    int b4 = tid >> 4, j = tid & 15, bo = b4 * 16;
    NT[(bo + j) * MP + bo + j] = 1.f;
    for (int t = j + 1; t < 16; ++t) {
      float s = 0.f;
      for (int sx = j; sx < t; ++sx)
        s += ML[(bo + t) * MP + bo + sx] * NT[(bo + j) * MP + bo + sx];
      NT[(bo + j) * MP + bo + t] = -s;
    }
  }
  __syncthreads();
  for (int lev = 1; lev <= 3; ++lev) {
    int nb = 4 - lev;
    for (int idx = tid; idx < nb * 256; idx += 1024) {
      int J = idx >> 8, I = J + lev;
      int i = (idx >> 4) & 15, j = idx & 15;
      float s = 0.f;
      for (int P = J; P < I; ++P)
#pragma unroll 4
        for (int p = 0; p < 16; ++p)
          s += ML[(16 * I + i) * MP + 16 * P + p] * NT[(16 * J + j) * MP + 16 * P + p];
      GB[J * 256 + i * 16 + j] = s;
    }
    __syncthreads();
    for (int idx = tid; idx < nb * 256; idx += 1024) {
      int J = idx >> 8, I = J + lev;
      int i = (idx >> 4) & 15, j = idx & 15;
      float s = 0.f;
#pragma unroll 4
      for (int p = 0; p < 16; ++p)
        s += NT[(16 * I + p) * MP + 16 * I + i] * GB[J * 256 + p * 16 + j];
      NT[(16 * J + j) * MP + 16 * I + i] = -s;
    }
    __syncthreads();
  }

  // (f) RHS_z = b * k * e^cg ; Z = N * RHS_z  (tiled store)
  {
    int tW = tid >> 4, g = tid & 15;
    float b = bL[tW];
#pragma unroll
    for (int i = 0; i < 2; ++i) {
      int d = g * 8 + 4 * i;
      float4 kv = *(const float4*)(kL + tW * PCH + d);
      float4 cg4 = *(const float4*)(cgL + tW * PCH + d);
      float4 r;
      r.x = b * kv.x * __expf(cg4.x); r.y = b * kv.y * __expf(cg4.y);
      r.z = b * kv.z * __expf(cg4.z); r.w = b * kv.w * __expf(cg4.w);
      *(float4*)(qL + tW * PCH + d) = r;
    }
  }
  __syncthreads();
  {
    int t2 = tid >> 5, c4 = tid & 31;
    float acc[2][4];
#pragma unroll
    for (int i = 0; i < 2; ++i)
#pragma unroll
      for (int j = 0; j < 4; ++j) acc[i][j] = 0.f;
    for (int s = 0; s < 64; ++s) {
      float2 nv = *(const float2*)(NT + s * MP + t2 * 2);
      float rv[4];
      *(float4*)rv = *(const float4*)(qL + s * PCH + c4 * 4);
#pragma unroll
      for (int j = 0; j < 4; ++j) {
        acc[0][j] += nv.x * rv[j];
        acc[1][j] += nv.y * rv[j];
      }
    }
    size_t zb = (size_t)bid * 8192 + (size_t)(c4 >> 2) * 1024 + (c4 & 3) * 4;
#pragma unroll
    for (int i = 0; i < 2; ++i) {
      float4 o; o.x = acc[i][0]; o.y = acc[i][1]; o.z = acc[i][2]; o.w = acc[i][3];
      *(float4*)(z_g + zb + (size_t)(t2 * 2 + i) * 16) = o;
    }
  }
  __syncthreads();

  // (g) RHS_v = b * silu(conv(v)) ; U0 = N * RHS_v (natural store)
  for (int it = 0; it < 8; ++it) {
    int cell = tid + (it << 10);
    int d = cell & 127, t = cell >> 7;
    int ch = 2 * CH1 + h * HD + d;
    float4 w4 = ((const float4*)cw)[ch];
    int rbase = t0 + t - 3;
    float acc;
    if (rbase >= 0) {
      const float* mp = mixed + (size_t)rbase * CH3 + ch;
      acc = mp[0] * w4.x + mp[CH3] * w4.y + mp[2 * CH3] * w4.z + mp[3 * CH3] * w4.w;
    } else {
      acc = 0.f;
      if (rbase + 0 >= 0) acc += mixed[(size_t)(rbase + 0) * CH3 + ch] * w4.x;
      if (rbase + 1 >= 0) acc += mixed[(size_t)(rbase + 1) * CH3 + ch] * w4.y;
      if (rbase + 2 >= 0) acc += mixed[(size_t)(rbase + 2) * CH3 + ch] * w4.z;
      acc += mixed[(size_t)(rbase + 3) * CH3 + ch] * w4.w;
    }
    acc = acc / (1.f + __expf(-acc));
    qL[t * PCH + d] = bL[t] * acc;
  }
  __syncthreads();
  {
    int t2 = tid >> 5, c4 = tid & 31;
    float acc[2][4];
#pragma unroll
    for (int i = 0; i < 2; ++i)
#pragma unroll
      for (int j = 0; j < 4; ++j) acc[i][j] = 0.f;
    for (int s = 0; s < 64; ++s) {
      float2 nv = *(const float2*)(NT + s * MP + t2 * 2);
      float rv[4];
      *(float4*)rv = *(const float4*)(qL + s * PCH + c4 * 4);
#pragma unroll
      for (int j = 0; j < 4; ++j) {
        acc[0][j] += nv.x * rv[j];
        acc[1][j] += nv.y * rv[j];
      }
    }
#pragma unroll
    for (int i = 0; i < 2; ++i) {
      size_t ob = ((size_t)(t0 + t2 * 2 + i) * NH + h) * HD + c4 * 4;
      float4 o; o.x = acc[i][0]; o.y = acc[i][1]; o.z = acc[i][2]; o.w = acc[i][3];
      *(float4*)(u0_g + ob) = o;
    }
  }
}

// ---------------------------------------------------------------------------
// Kernel B v6: 1024 threads (16 waves -> 4 waves/SIMD; grid 256 = 1 block/CU
// so occupancy must come from block width -- R3 showed grid-widening
// duplicates kxt-shaped traffic across blocks). Work split finer:
//   phase1: [hi512: prev-chunk P4] || [all 1024: P1, 16 d-groups of 8]
//   phase2: [lo512: T-reduce (one (t,j) each, 16 partials) -> Un/Ut]
//           [hi512: O-reduce -> regs]
//   phase3: [lo512: P5, 128k x 4 j-pairs] || [hi512: P3, 8 s-groups of 8]
// Same 3-barrier/chunk schedule and conflict-free pitches as v5 (verified 0).
// ---------------------------------------------------------------------------
#define PT 68
#define PG 544   // 8 j * 68

__global__ __launch_bounds__(1024, 4)
void kda_scan3(const float* __restrict__ qt_g, const float* __restrict__ kbt_g,
               const float* __restrict__ u0_g, const float* __restrict__ z_g,
               const float* __restrict__ w_g, const float* __restrict__ ecg_g,
               float* __restrict__ out, float* __restrict__ slabs) {
  __shared__ float Tp[8704], Op[8704];   // [16g][8j][68]
  __shared__ float Wp[4352];             // [8g][8j][68]
  __shared__ float Sl[1536];             // [128 k][12 pitch] (8 j used)
  __shared__ float Un[512];              // [64 t][8 j]
  __shared__ float Ut[544];              // [8 j][68]
  (void)slabs;
  const int tid = threadIdx.x;
  const int bid = blockIdx.x;
  const int h = bid & 15, vg = bid >> 4;
  const int gA = tid >> 6, tA = tid & 63;   // P1: 16 d-groups x 64 t
  const int tH = (tid >> 3) & 63, jS = tid & 7;  // P2/P4: (t, j) singles
  const int kC = tid & 127;                 // lo: S row
  const int jp = (tid >> 7) & 3;            // lo: j-pair index (j = 2jp, 2jp+1)
  const int gB = (tid >> 6) & 7;            // hi: s-group 0..7

  for (int i = tid; i < 1536; i += 1024) Sl[i] = 0.f;
  __syncthreads();

  float OsV = 0.f;                          // hi: deferred O1 sum

  for (int c = 0; c < NC; ++c) {
    const int ch = c * 16 + h;
    // ---- loads for chunk c, issued up front ----
    float z8[8], q8[8];
    {
      const size_t base = (size_t)ch * 8192 + (size_t)(gA >> 1) * 1024 + tA * 16 + (gA & 1) * 8;
      const float* zb = z_g + base;
      const float* qb = qt_g + base;
      *(float4*)z8       = *(const float4*)(zb);
      *(float4*)(z8 + 4) = *(const float4*)(zb + 4);
      *(float4*)q8       = *(const float4*)(qb);
      *(float4*)(q8 + 4) = *(const float4*)(qb + 4);
    }
    float kv[64], eC = 0.f, u0v = 0.f, w8[8];
    if (tid < 512) {
      const float* kb = kbt_g + (size_t)ch * 8192 + (size_t)kC * 64;
#pragma unroll
      for (int t4 = 0; t4 < 16; ++t4)
        *(float4*)(kv + 4 * t4) = *(const float4*)(kb + 4 * t4);
      eC = ecg_g[(size_t)ch * 128 + kC];
      u0v = u0_g[((size_t)(c * 64 + tH) * NH + h) * HD + vg * 8 + jS];
    } else {
      const float* wb = w_g + (size_t)ch * 4096 + (size_t)gB * 512 + tA * 8;
      *(float4*)w8       = *(const float4*)(wb);
      *(float4*)(w8 + 4) = *(const float4*)(wb + 4);
    }

    // ---- phase1: [hi: prev-chunk P4] || [all: P1 partials] ----
    if (tid >= 512 && c > 0) {
      float O2 = 0.f;
#pragma unroll
      for (int g = 0; g < 8; ++g) O2 += Wp[g * PG + jS * PT + tH];
      out[((size_t)((c - 1) * 64 + tH) * NH + h) * HD + vg * 8 + jS] = OsV + O2;
    }
    {
      float Ta[8], Oa[8];
#pragma unroll
      for (int j = 0; j < 8; ++j) { Ta[j] = 0.f; Oa[j] = 0.f; }
#pragma unroll
      for (int dd = 0; dd < 8; ++dd) {
        float s8[8];
        const float* sr = Sl + (gA * 8 + dd) * 12;
        *(float4*)s8 = *(const float4*)(sr);
        *(float4*)(s8 + 4) = *(const float4*)(sr + 4);
        float zz = z8[dd], qq = q8[dd];
#pragma unroll
        for (int j = 0; j < 8; ++j) { Ta[j] += zz * s8[j]; Oa[j] += qq * s8[j]; }
      }
#pragma unroll
      for (int j = 0; j < 8; ++j) {
        Tp[gA * PG + j * PT + tA] = Ta[j];
        Op[gA * PG + j * PT + tA] = Oa[j];
      }
    }
    __syncthreads();

    // ---- phase2: [lo: T-reduce -> U] || [hi: O-reduce -> regs] ----
    if (tid < 512) {
      float Ts = 0.f;
#pragma unroll
      for (int g = 0; g < 16; ++g) Ts += Tp[g * PG + jS * PT + tH];
      float U = u0v - Ts;
      Un[tH * 8 + jS] = U;
      Ut[jS * PT + tH] = U;
    } else {
      float Os = 0.f;
#pragma unroll
      for (int g = 0; g < 16; ++g) Os += Op[g * PG + jS * PT + tH];
      OsV = Os;
    }
    __syncthreads();

    // ---- phase3: [lo: P5 S-update] || [hi: P3 W*U partials -> Wp] ----
    if (tid < 512) {
      float a0 = 0.f, a1 = 0.f;
      const float* u0r = Ut + (2 * jp) * PT;
      const float* u1r = Ut + (2 * jp + 1) * PT;
#pragma unroll
      for (int t4 = 0; t4 < 16; ++t4) {
        float k0 = kv[4 * t4], k1 = kv[4 * t4 + 1], k2 = kv[4 * t4 + 2], k3 = kv[4 * t4 + 3];
        float4 ua = *(const float4*)(u0r + 4 * t4);
        float4 ub = *(const float4*)(u1r + 4 * t4);
        a0 += k0 * ua.x + k1 * ua.y + k2 * ua.z + k3 * ua.w;
        a1 += k0 * ub.x + k1 * ub.y + k2 * ub.z + k3 * ub.w;
      }
      float* sp = Sl + kC * 12 + 2 * jp;
      float2 s = *(float2*)sp;
      s.x = eC * s.x + a0;
      s.y = eC * s.y + a1;
      *(float2*)sp = s;
    } else {
      float Wa[8];
#pragma unroll
      for (int j = 0; j < 8; ++j) Wa[j] = 0.f;
#pragma unroll
      for (int sp = 0; sp < 8; ++sp) {
        const float* ur = Un + (gB * 8 + sp) * 8;
        float u8[8];
        *(float4*)u8 = *(const float4*)(ur);
        *(float4*)(u8 + 4) = *(const float4*)(ur + 4);
        float wv = w8[sp];
#pragma unroll
        for (int j = 0; j < 8; ++j) Wa[j] += wv * u8[j];
      }
#pragma unroll
      for (int j = 0; j < 8; ++j) Wp[gB * PG + j * PT + tA] = Wa[j];
    }
    __syncthreads();
  }

  // ---- epilogue: final P4 for chunk NC-1 ----
  if (tid >= 512) {
    float O2 = 0.f;
#pragma unroll
    for (int g = 0; g < 8; ++g) O2 += Wp[g * PG + jS * PT + tH];
    out[((size_t)((NC - 1) * 64 + tH) * NH + h) * HD + vg * 8 + jS] = OsV + O2;
  }
}

// ---------------------------------------------------------------------------
extern "C" void kernel_launch(void* const* d_in, const int* in_sizes, int n_in,
                              void* d_out, int out_size, void* d_ws, size_t ws_size,
                              hipStream_t stream) {
  const float* mixed = (const float*)d_in[0];
  const float* fg    = (const float*)d_in[1];
  const float* beta  = (const float*)d_in[2];
  const float* cw    = (const float*)d_in[3];
  const float* dtb   = (const float*)d_in[4];
  const float* alog  = (const float*)d_in[5];
  float* ws = (float*)d_ws;
  float* qt_g  = ws + QT_OFF;
  float* kbt_g = ws + KBT_OFF;
  float* u0_g  = ws + U0_OFF;
  float* z_g   = ws + Z_OFF;
  float* w_g   = ws + W_OFF;
  float* ecg_g = ws + ECG_OFF;
  float* slabs = ws + SLAB_OFF;

  hipLaunchKernelGGL(kda_chunk, dim3(NC * NH), dim3(1024), 0, stream,
                     mixed, fg, beta, cw, dtb, alog,
                     qt_g, kbt_g, u0_g, z_g, w_g, ecg_g);
  hipLaunchKernelGGL(kda_scan3, dim3(256), dim3(1024), 0, stream,
                     qt_g, kbt_g, u0_g, z_g, w_g, ecg_g, (float*)d_out, slabs);
  (void)in_sizes; (void)n_in; (void)out_size; (void)ws_size;
}